// Round 2
// baseline (310.642 us; speedup 1.0000x reference)
//
#include <hip/hip_runtime.h>
#include <math.h>

// Problem constants (from reference): T=4096, N=16, D=512.
#define T_  4096
#define D_  512
#define N_  16
#define S_  32            // number of time segments
#define L_  128           // T_/S_  segment length
#define ND_  (N_*D_)      // 8192 chains
#define SND_ (S_*ND_)     // 262144 segment-threads

// K1: per (s,n,d) run ha-recurrence from 0 over its segment -> particular P[s].
__global__ __launch_bounds__(256) void k1_seg_ha(const float* __restrict__ x,
                                                 const float* __restrict__ alpha,
                                                 float* __restrict__ P) {
    int gid = blockIdx.x * 256 + threadIdx.x;      // [0, SND_)
    int d   = gid & (D_ - 1);
    int nd  = gid & (ND_ - 1);
    int s   = gid >> 13;                           // / ND_
    float a  = alpha[nd];
    float ha = 0.0f;
    const float* xp = x + (size_t)s * L_ * D_ + d;
    #pragma unroll 4
    for (int t = 0; t < L_; ++t) {
        float xv = xp[(size_t)t * D_];
        ha = fmaf(a, xv - ha, ha);                 // ha += a*(x-ha)
    }
    P[gid] = ha;
}

// K2: per (n,d) prefix across segments for ha; also writes final ha_N.
__global__ __launch_bounds__(256) void k2_prefix_ha(const float* __restrict__ h_a,
                                                    const float* __restrict__ alpha,
                                                    const float* __restrict__ P,
                                                    float* __restrict__ haStart,
                                                    float* __restrict__ out_ha_final) {
    int nd = blockIdx.x * 256 + threadIdx.x;       // [0, ND_)
    float a  = alpha[nd];
    float cL = powf(1.0f - a, (float)L_);
    float ha = h_a[nd];
    #pragma unroll
    for (int s = 0; s < S_; ++s) {
        haStart[s * ND_ + nd] = ha;
        ha = fmaf(cL, ha, P[s * ND_ + nd]);
    }
    out_ha_final[nd] = ha;
}

// K3: per (s,n,d) with known ha_start, run hv-recurrence from 0 -> Q[s].
__global__ __launch_bounds__(256) void k3_seg_hv(const float* __restrict__ x,
                                                 const float* __restrict__ alpha,
                                                 const float* __restrict__ haStart,
                                                 float* __restrict__ Q) {
    int gid = blockIdx.x * 256 + threadIdx.x;
    int d   = gid & (D_ - 1);
    int nd  = gid & (ND_ - 1);
    int s   = gid >> 13;
    float a  = alpha[nd];
    float c  = 1.0f - a;
    float ha = haStart[gid];
    float hv = 0.0f;
    const float* xp = x + (size_t)s * L_ * D_ + d;
    #pragma unroll 2
    for (int t = 0; t < L_; ++t) {
        float xv = xp[(size_t)t * D_];
        float dd = xv - ha;
        hv = c * fmaf(a, dd * dd, hv);             // hv = (1-a)*(hv + a*d*d)
        ha = fmaf(a, dd, ha);                      // ha += a*d
    }
    Q[gid] = hv;
}

// K4: per (n,d) prefix across segments for hv (init h_s^2); writes final sqrt(hv_N).
__global__ __launch_bounds__(256) void k4_prefix_hv(const float* __restrict__ h_s,
                                                    const float* __restrict__ alpha,
                                                    const float* __restrict__ Q,
                                                    float* __restrict__ hvStart,
                                                    float* __restrict__ out_hs_final) {
    int nd = blockIdx.x * 256 + threadIdx.x;
    float a  = alpha[nd];
    float cL = powf(1.0f - a, (float)L_);
    float hs = h_s[nd];
    float hv = hs * hs;
    #pragma unroll
    for (int s = 0; s < S_; ++s) {
        hvStart[s * ND_ + nd] = hv;
        hv = fmaf(cL, hv, Q[s * ND_ + nd]);
    }
    out_hs_final[nd] = sqrtf(hv);
}

// K5: per (s,n,d) run the exact reference recurrence from correct start states,
// writing out_a and out_s for every t in the segment. 268 MB coalesced stores.
__global__ __launch_bounds__(256) void k5_out(const float* __restrict__ x,
                                              const float* __restrict__ alpha,
                                              const float* __restrict__ haStart,
                                              const float* __restrict__ hvStart,
                                              float* __restrict__ out) {
    int gid = blockIdx.x * 256 + threadIdx.x;
    int d   = gid & (D_ - 1);
    int n   = (gid >> 9) & (N_ - 1);
    int nd  = gid & (ND_ - 1);
    int s   = gid >> 13;
    float a  = alpha[nd];
    float c  = 1.0f - a;
    float ha = haStart[gid];
    float hv = hvStart[gid];
    const float* xp = x + (size_t)s * L_ * D_ + d;
    // out row for time t=(s*L_+tt): base (t*2N + n)*D + d ; out_s adds N*D.
    float* oa = out + (size_t)s * L_ * 2 * ND_ + (size_t)n * D_ + d;
    float* os = oa + ND_;
    #pragma unroll 2
    for (int t = 0; t < L_; ++t) {
        float xv = xp[(size_t)t * D_];
        float dd = xv - ha;
        hv = c * fmaf(a, dd * dd, hv);
        ha = fmaf(a, dd, ha);
        oa[(size_t)t * 2 * ND_] = ha;
        os[(size_t)t * 2 * ND_] = sqrtf(hv);
    }
}

extern "C" void kernel_launch(void* const* d_in, const int* in_sizes, int n_in,
                              void* d_out, int out_size, void* d_ws, size_t ws_size,
                              hipStream_t stream) {
    const float* x     = (const float*)d_in[0];   // [T, D]
    const float* h_a   = (const float*)d_in[1];   // [N, D]
    const float* h_s   = (const float*)d_in[2];   // [N, D]
    const float* alpha = (const float*)d_in[3];   // [N, D]
    float* out = (float*)d_out;                   // [T, 2N, D] ++ ha_N ++ sqrt(hv_N)

    float* ws      = (float*)d_ws;                // needs 4*SND_ floats = 4 MiB
    float* P       = ws;                          // [S, N, D]
    float* haStart = ws + SND_;                   // [S, N, D]
    float* Q       = ws + 2 * (size_t)SND_;       // [S, N, D]
    float* hvStart = ws + 3 * (size_t)SND_;       // [S, N, D]

    float* out_ha_final = out + (size_t)T_ * 2 * ND_;   // [N, D]
    float* out_hs_final = out_ha_final + ND_;           // [N, D]

    dim3 b(256);
    dim3 segGrid(SND_ / 256);   // 1024 blocks
    dim3 chGrid(ND_ / 256);     // 32 blocks

    k1_seg_ha<<<segGrid, b, 0, stream>>>(x, alpha, P);
    k2_prefix_ha<<<chGrid, b, 0, stream>>>(h_a, alpha, P, haStart, out_ha_final);
    k3_seg_hv<<<segGrid, b, 0, stream>>>(x, alpha, haStart, Q);
    k4_prefix_hv<<<chGrid, b, 0, stream>>>(h_s, alpha, Q, hvStart, out_hs_final);
    k5_out<<<segGrid, b, 0, stream>>>(x, alpha, haStart, hvStart, out);
}